// Round 4
// baseline (470.690 us; speedup 1.0000x reference)
//
#include <hip/hip_runtime.h>

#define W 320

typedef __attribute__((ext_vector_type(8))) short   short8;
typedef __attribute__((ext_vector_type(4))) float   floatx4;

__device__ __forceinline__ unsigned int f2bf(float f) {
    // round-to-nearest-even fp32 -> bf16 (low 16 bits)
    unsigned int u = __float_as_uint(f);
    u += 0x7FFFu + ((u >> 16) & 1u);
    return u >> 16;
}

// One block per (b,h) row, sliding-window ring in LDS.
// Ring: 192 R-rows as bf16, slot = (k + 64) % 192, 48 KB -> 3 blocks/CU.
// Row processed in 5 chunks of 64 j's. During chunk c we compute with the
// window k in [64c-64, 64c+64) (ring thirds {c, c+1} mod 3) while staging
// k in [64c+64, 64c+128) into third {c+2} mod 3 -> provably disjoint, so a
// single __syncthreads per chunk. Stage loads issue BEFORE the MFMA cluster
// and are ds_written after it: HBM latency hides under compute, and global
// load issue is spread over the whole kernel (no front-loaded burst).
// XOR swizzle chunk' = chunk ^ (slot & 15) keeps ds_read_b128 conflict-free.
__global__ __launch_bounds__(512, 6)
void cost_volume_kernel(const float* __restrict__ Lg,
                        const float* __restrict__ Rg,
                        float* __restrict__ out) {
    __shared__ unsigned short S[192 * 128];   // 48 KB

    // XCD-chunked swizzle: 1280 = 8 x 160
    const int lin = blockIdx.x;
    const int bh  = (lin & 7) * 160 + (lin >> 3);
    const int tid = threadIdx.x;

    // staging decomposition: 32 threads per row, 16 rows per pass
    const int lr    = tid >> 5;          // 0..15
    const int half  = tid & 1;
    const int chunk = (tid & 31) >> 1;   // 0..15
    const int cf    = (tid & 31) << 2;   // float offset 0..124

    // wave decomposition: 8 waves = 4 local m-tiles x 2 n-groups
    const int wave = tid >> 6;
    const int lane = tid & 63;
    const int col  = lane & 15;
    const int quad = lane >> 4;
    const int lm   = wave >> 1;          // local m-tile 0..3
    const int g    = wave & 1;           // g=0: t{0,1,2}; g=1: t{3,4}
    const int NT   = g ? 2 : 3;
    const int tb   = g * 3;

    const float* Rrow0 = Rg + (size_t)bh * W * 128;
    const float* Lrow0 = Lg + (size_t)bh * W * 128;
    float* obase = out + (size_t)bh * W * 64;

    // ---- prologue: stage k in [0, 64) -> slots 64..127 ----
    // (slots 0..63 would hold k<0; they are never read in chunk 0 thanks to
    //  the kt>=0 guard, and get overwritten at chunk 1.)
    #pragma unroll
    for (int p = 0; p < 4; ++p) {
        const int k    = p * 16 + lr;
        const int slot = k + 64;
        floatx4 v = *(const floatx4*)(Rrow0 + (size_t)k * 128 + cf);
        uint2 d;
        d.x = f2bf(v.x) | (f2bf(v.y) << 16);
        d.y = f2bf(v.z) | (f2bf(v.w) << 16);
        const int sw = chunk ^ (slot & 15);
        *(uint2*)&S[slot * 128 + (sw << 3) + half * 4] = d;
    }
    __syncthreads();

    #pragma unroll
    for (int c = 0; c < 5; ++c) {
        const int jc = c * 64;
        const int m0 = jc + lm * 16;

        // -- issue A loads (L rows; g-pair duplicate hits L1/L2) --
        const float* Arow = Lrow0 + (size_t)(m0 + col) * 128 + quad * 8;
        floatx4 alo[4], ahi[4];
        #pragma unroll
        for (int ks = 0; ks < 4; ++ks) {
            alo[ks] = *(const floatx4*)(Arow + ks * 32);
            ahi[ks] = *(const floatx4*)(Arow + ks * 32 + 4);
        }

        // -- issue stage loads for next chunk: k in [jc+64, jc+128) --
        floatx4 sv[4];
        if (c < 4) {
            #pragma unroll
            for (int p = 0; p < 4; ++p) {
                const int k = jc + 64 + p * 16 + lr;
                sv[p] = *(const floatx4*)(Rrow0 + (size_t)k * 128 + cf);
            }
        }

        // -- convert A --
        short8 af[4];
        #pragma unroll
        for (int ks = 0; ks < 4; ++ks) {
            short8 a;
            a[0] = (short)f2bf(alo[ks].x); a[1] = (short)f2bf(alo[ks].y);
            a[2] = (short)f2bf(alo[ks].z); a[3] = (short)f2bf(alo[ks].w);
            a[4] = (short)f2bf(ahi[ks].x); a[5] = (short)f2bf(ahi[ks].y);
            a[6] = (short)f2bf(ahi[ks].z); a[7] = (short)f2bf(ahi[ks].w);
            af[ks] = a;
        }

        // -- MFMA: n-tiles kt = m0-64+t*16, window slots (kt+64)%192 --
        floatx4 acc[3];
        #pragma unroll
        for (int t = 0; t < 3; ++t) {
            acc[t].x = 0.f; acc[t].y = 0.f; acc[t].z = 0.f; acc[t].w = 0.f;
        }
        #pragma unroll
        for (int t = 0; t < 3; ++t) {
            if (t < NT) {
                const int kt = m0 - 64 + (tb + t) * 16;
                if (kt >= 0) {                       // wave-uniform
                    const int x    = kt + 64 + col;  // < 384
                    const int slot = x - (x >= 192 ? 192 : 0);  // (slot&15)==col
                    #pragma unroll
                    for (int ks = 0; ks < 4; ++ks) {
                        const int sc = (ks * 4 + quad) ^ col;
                        const short8 bf = *(const short8*)&S[slot * 128 + (sc << 3)];
                        acc[t] = __builtin_amdgcn_mfma_f32_16x16x32_bf16(af[ks], bf, acc[t], 0, 0, 0);
                    }
                }
            }
        }

        // -- epilogue: col=n, row=quad*4+r=m; i = 64 + m - (tb+t)*16 - col --
        #pragma unroll
        for (int t = 0; t < 3; ++t) {
            if (t < NT) {
                #pragma unroll
                for (int r = 0; r < 4; ++r) {
                    const int m = quad * 4 + r;
                    const int i = 64 + m - (tb + t) * 16 - col;
                    if (i >= 0 && i < 64) {
                        obase[(size_t)(m0 + m) * 64 + i] = acc[t][r] * 0.0078125f;
                    }
                }
            }
        }

        // -- write staged rows into ring third {c+2} mod 3 --
        if (c < 4) {
            #pragma unroll
            for (int p = 0; p < 4; ++p) {
                const int x    = jc + 128 + p * 16 + lr;      // k + 64, < 384
                const int slot = x - (x >= 192 ? 192 : 0);
                uint2 d;
                d.x = f2bf(sv[p].x) | (f2bf(sv[p].y) << 16);
                d.y = f2bf(sv[p].z) | (f2bf(sv[p].w) << 16);
                const int sw = chunk ^ (slot & 15);
                *(uint2*)&S[slot * 128 + (sw << 3) + half * 4] = d;
            }
        }

        __syncthreads();
    }
}

extern "C" void kernel_launch(void* const* d_in, const int* in_sizes, int n_in,
                              void* d_out, int out_size, void* d_ws, size_t ws_size,
                              hipStream_t stream) {
    const float* L = (const float*)d_in[0];
    const float* R = (const float*)d_in[1];
    float* out = (float*)d_out;
    dim3 grid(8 * 160);   // one block per (b,h) row
    cost_volume_kernel<<<grid, 512, 0, stream>>>(L, R, out);
}

// Round 5
// 443.133 us; speedup vs baseline: 1.0622x; 1.0622x over previous
//
#include <hip/hip_runtime.h>

#define W 320

typedef __attribute__((ext_vector_type(8))) short   short8;
typedef __attribute__((ext_vector_type(4))) float   floatx4;

__device__ __forceinline__ unsigned int f2bf(float f) {
    // round-to-nearest-even fp32 -> bf16 (low 16 bits)
    unsigned int u = __float_as_uint(f);
    u += 0x7FFFu + ((u >> 16) & 1u);
    return u >> 16;
}

// Load one 16-row tile fragment set: per lane 4x 32 B (= row col of the tile,
// float elems quad*8 + q*32 .. +8). base already includes (bh*W+col)*128+quad*8.
#define LOAD8(buf, base, toff) do {                                         \
    const float* p_ = (base) + (size_t)(toff) * 2048;                       \
    _Pragma("unroll")                                                       \
    for (int q_ = 0; q_ < 4; ++q_) {                                        \
        buf[2*q_]   = *(const floatx4*)(p_ + q_*32);                        \
        buf[2*q_+1] = *(const floatx4*)(p_ + q_*32 + 4);                    \
    } } while (0)

// Convert 8x floatx4 raw -> 4x short8 bf16 fragments (RNE, matches harness).
#define CONV8(dst, buf) do {                                                \
    _Pragma("unroll")                                                       \
    for (int q_ = 0; q_ < 4; ++q_) {                                        \
        short8 x_;                                                          \
        x_[0] = (short)f2bf(buf[2*q_].x);   x_[1] = (short)f2bf(buf[2*q_].y);   \
        x_[2] = (short)f2bf(buf[2*q_].z);   x_[3] = (short)f2bf(buf[2*q_].w);   \
        x_[4] = (short)f2bf(buf[2*q_+1].x); x_[5] = (short)f2bf(buf[2*q_+1].y); \
        x_[6] = (short)f2bf(buf[2*q_+1].z); x_[7] = (short)f2bf(buf[2*q_+1].w); \
        (dst)[q_] = x_;                                                     \
    } } while (0)

// Barrier-free streaming cost volume. One wave owns 5 consecutive m-tiles
// (80 j's) of one (b,h) row. B-operand (R) window = 5-tile register ring
// Bf[5][4] (invariant: Bf[s] holds tile t with t % 5 == s); each step loads
// exactly one new R tile and one L tile, software-pipelined one iteration
// ahead so ~16 KB of loads is in flight under every compute phase. No LDS,
// no __syncthreads, no vmcnt(0) convoys -- streaming-kernel shape.
__global__ __launch_bounds__(256, 2)
void cost_volume_kernel(const float* __restrict__ Lg,
                        const float* __restrict__ Rg,
                        float* __restrict__ out) {
    // XCD-chunked swizzle: 1280 = 8 x 160, bijective
    const int lin = blockIdx.x;
    const int bh  = (lin & 7) * 160 + (lin >> 3);
    const int tid = threadIdx.x;
    const int w    = tid >> 6;          // wave 0..3 = chunk of 5 m-tiles
    const int lane = tid & 63;
    const int col  = lane & 15;
    const int quad = lane >> 4;

    const float* Rb = Rg + ((size_t)bh * W + col) * 128 + quad * 8;
    const float* Lb = Lg + ((size_t)bh * W + col) * 128 + quad * 8;
    float* obase = out + (size_t)bh * W * 64;

    floatx4 rbufA[8], rbufB[8], abuf[8];
    short8  Bf[5][4];
    short8  Af[4];

    const int T0 = 5 * w;               // first m-tile of this wave's chunk

    // ---- prologue: fill ring with tiles T0-4 .. T0 (skip negatives), A(T0) --
    if (T0 >= 4) LOAD8(rbufA, Rb, T0 - 4);
    if (T0 >= 3) LOAD8(rbufB, Rb, T0 - 3);
    LOAD8(abuf, Lb, T0);
    if (T0 >= 4) CONV8(Bf[1], rbufA);   // tile T0-4 ≡ 1 (mod 5)
    if (T0 >= 2) LOAD8(rbufA, Rb, T0 - 2);
    if (T0 >= 3) CONV8(Bf[2], rbufB);
    if (T0 >= 1) LOAD8(rbufB, Rb, T0 - 1);
    if (T0 >= 2) CONV8(Bf[3], rbufA);
    LOAD8(rbufA, Rb, T0);
    if (T0 >= 1) CONV8(Bf[4], rbufB);
    CONV8(Bf[0], rbufA);

    // ---- main loop: 5 m-tiles, fully unrolled (all reg indices static) ----
    #pragma unroll
    for (int u = 0; u < 5; ++u) {
        CONV8(Af, abuf);                         // A(T0+u), loaded last iter

        if (u < 4) {                             // prefetch next tile pair
            LOAD8(abuf,  Lb, T0 + u + 1);
            LOAD8(rbufA, Rb, T0 + u + 1);
        }

        floatx4 acc[5];
        #pragma unroll
        for (int v = 0; v < 5; ++v) {
            acc[v].x = 0.f; acc[v].y = 0.f; acc[v].z = 0.f; acc[v].w = 0.f;
        }

        // n-tiles: tile T0+u-4+v, v=0..4; ring slot = (u+1+v)%5 (static)
        #pragma unroll
        for (int v = 0; v < 5; ++v) {
            if (T0 + u + v >= 4) {               // tile >= 0, wave-uniform
                #pragma unroll
                for (int ks = 0; ks < 4; ++ks) {
                    acc[v] = __builtin_amdgcn_mfma_f32_16x16x32_bf16(
                        Af[ks], Bf[(u + 1 + v) % 5][ks], acc[v], 0, 0, 0);
                }
            }
        }

        // ---- stores: j = (T0+u)*16 + m, m = quad*4+r, n-row k = tile*16+col,
        // i = j-k = 64 - 16v + m - col. v=1..3 always in [0,64); v=0 needs
        // m<col, v=4 needs m>=col. Skipped tiles store the required zeros.
        float* orow = obase + (size_t)(T0 + u) * 16 * 64;
        #pragma unroll
        for (int v = 0; v < 5; ++v) {
            #pragma unroll
            for (int r = 0; r < 4; ++r) {
                const int m = quad * 4 + r;
                const int i = 64 - 16 * v + m - col;
                const bool ok = (v == 0) ? (m < col) : (v == 4) ? (m >= col) : true;
                if (ok) orow[(size_t)m * 64 + i] = acc[v][r] * 0.0078125f;  // /128
            }
        }

        if (u < 4) CONV8(Bf[(u + 1) % 5], rbufA);  // ring-insert tile T0+u+1
    }
}

extern "C" void kernel_launch(void* const* d_in, const int* in_sizes, int n_in,
                              void* d_out, int out_size, void* d_ws, size_t ws_size,
                              hipStream_t stream) {
    const float* L = (const float*)d_in[0];
    const float* R = (const float*)d_in[1];
    float* out = (float*)d_out;
    dim3 grid(8 * 160);   // one block per (b,h) row, 4 waves = 4 chunks
    cost_volume_kernel<<<grid, 256, 0, stream>>>(L, R, out);
}